// Round 15
// baseline (2359.026 us; speedup 1.0000x reference)
//
#include <hip/hip_runtime.h>
#include <hip/hip_bf16.h>
#include <type_traits>

typedef short bf16x8 __attribute__((ext_vector_type(8)));
typedef short bf16x4 __attribute__((ext_vector_type(4)));
typedef float f32x4  __attribute__((ext_vector_type(4)));
typedef int   i32x4  __attribute__((ext_vector_type(4)));
typedef unsigned long long u64;

#define B_   64
#define T_   512
#define XD_  256
#define H_   1024
#define NWG  256
#define NTH  512

// workspace layout (bytes)
#define OFF_WCAT  0UL
#define SZ_WCAT   (3072UL*1280*2)                 // 7,864,320
#define OFF_XB    (OFF_WCAT + SZ_WCAT)
#define SZ_XB     ((unsigned long)T_*B_*XD_*2)    // 16,777,216
#define OFF_HBF16 (OFF_XB + SZ_XB)
#define SZ_HBF16  (2UL*B_*H_*2)                   // 262,144
#define OFF_PLAN  (OFF_HBF16 + SZ_HBF16)
#define SZ_PLAN   (4096UL)
#define OFF_FLAG  (OFF_PLAN + SZ_PLAN)            // 4 domains x 64 ints (2 lines ea)
#define SZ_FLAG   (4096UL)

#define WAITV(n) do { asm volatile("s_waitcnt vmcnt(" #n ")" ::: "memory"); \
                      __builtin_amdgcn_sched_barrier(0); } while (0)

__device__ __forceinline__ float sigm_(float x) { return 1.f / (1.f + __expf(-x)); }
__device__ __forceinline__ float tanh_(float x) { return 1.f - 2.f / (__expf(2.f * x) + 1.f); }
__device__ __forceinline__ short bf16_of(float f) {
    __hip_bfloat16 h = __float2bfloat16(f);
    return *reinterpret_cast<short*>(&h);
}
__device__ __forceinline__ float f_of_bf16(short s) {
    union { unsigned u; float f; } c;
    c.u = ((unsigned)(unsigned short)s) << 16;
    return c.f;
}

// ---- prep: concat W_ih|W_hh into bf16 Wcat[3072][1280] ----
__global__ void prep_wcat(const float* __restrict__ W_ih, const float* __restrict__ W_hh,
                          short* __restrict__ Wcat) {
    const int j = blockIdx.x;
    for (int k = threadIdx.x; k < 1280; k += 256) {
        float v = (k < XD_) ? W_ih[j * XD_ + k] : W_hh[j * H_ + (k - XD_)];
        Wcat[(long)j * 1280 + k] = bf16_of(v);
    }
}

// ---- prep: transpose x [B][T][X] f32 -> xb [T][B][X] bf16 ----
__global__ void prep_xb(const float* __restrict__ x, short* __restrict__ xb) {
    const long total = (long)T_ * B_ * XD_;
    for (long i = (long)blockIdx.x * blockDim.x + threadIdx.x; i < total;
         i += (long)gridDim.x * blockDim.x) {
        int t   = (int)(i >> 14);
        int rem = (int)(i & 16383);
        int b   = rem >> 8;
        int k   = rem & 255;
        xb[i] = bf16_of(x[((long)(b * T_ + t)) * XD_ + k]);
    }
}

// ---- prep: packed per-step skip plan: bit0=alpha, bit1=beta, bits2+=lag ----
__global__ void prep_plan(const int* __restrict__ w1, const int* __restrict__ w2,
                          const int* __restrict__ ssp, int* __restrict__ plang) {
    int t = threadIdx.x;
    if (t > T_) return;
    if (t == T_) { plang[t] = (1 << 2); return; }
    int ss = ssp[0];
    int a = w1[t] & 1;
    int uz = 0, slot = 0;
    if (t < ss)            { if (2 * t < ss) uz = 1; else slot = ss - t - 1; }
    else if (t - ss < ss)  { uz = 1; }
    else                   { slot = 2 * ss - 1; }
    int bet = uz ? 0 : (w2[t] & 1);
    plang[t] = a | (bet << 1) | ((slot + 1) << 2);
}

// ---- prep: zero h16 slot0 + flags via sc01 (re-runs every graph replay) ----
__global__ void prep_zero(short* __restrict__ hbf16, int* __restrict__ flags) {
    int i = blockIdx.x * blockDim.x + threadIdx.x;
    if (i < B_ * H_) hbf16[i] = 0;
    if (i < 1024) {
        int* p = flags + i;
        int z = 0;
        asm volatile("global_store_dword %0, %1, off sc0 sc1" :: "v"(p), "v"(z) : "memory");
    }
}

// ---- persistent kernel: 256 WGs x 512 thr = 64 col-blocks x 4 batch-domains ----
// R14 fabric (per-WG sc01 flags, wave1-only poll, sc01 MALL h exchange, wave0
// x-GEMM in the A->B window). New: counted-vmcnt h-GEMM (W frags pre-read to
// VGPRs), 2-deep pipelined flag poll, poller wave gets smallest K slice.
__global__ __launch_bounds__(NTH, 1) void persist_kernel(
    const short* __restrict__ Wcat, const short* __restrict__ xb,
    const float* __restrict__ b_ih, const float* __restrict__ b_hh,
    short* __restrict__ hbf16, const int* __restrict__ plang,
    int* __restrict__ flags, float* __restrict__ out) {

    __shared__ short Wlds[48 * 1280];        // 122,880 B (XOR-swizzled rows)
    __shared__ float red[3][7][64][4];       // 21,504 B  H partials (waves 1-7)
    __shared__ short ringl[16][16][20];      // 10,240 B  bf16 h history (skip path)
    __shared__ float hbls[2][16][20];        // 2,560 B   f32 blended-h (z path)
    __shared__ int   planl[T_ + 1];          // 2,052 B

    const int tid = threadIdx.x;
    const int w   = tid >> 6;           // wave 0..7
    const int l   = tid & 63;
    const int l15 = l & 15;
    const int lhi = l >> 4;
    const int wg  = blockIdx.x;
    const int c0  = (wg >> 2) << 4;     // 16 h-cols per WG
    const int m0  = (wg & 3) << 4;      // 16 batch rows per WG (sync domain)
    const int dom = wg & 3;
    const int cblk = wg >> 2;           // col-block 0..63
    const int jc0 = c0 + lhi * 4;

    // --- one-time: W slice -> LDS (swizzled: byte ^= (row&15)<<4), plan, zeros ---
    for (int j = tid; j < 48 * 160; j += NTH) {
        int r    = j / 160;
        int cbyt = (j - r * 160) * 16;
        int g    = r >> 4, i = r & 15;
        bf16x8 v = *(const bf16x8*)(Wcat + (long)(g * H_ + c0 + i) * 1280 + (cbyt >> 1));
        *(bf16x8*)((char*)Wlds + r * 2560 + (cbyt ^ (i << 4))) = v;
    }
    for (int j = tid; j <= T_; j += NTH) planl[j] = plang[j];
    for (int j = tid; j < 2 * 16 * 20; j += NTH) ((float*)hbls)[j] = 0.f;
    for (int j = tid; j < 16 * 16 * 20; j += NTH) ((short*)ringl)[j] = 0;

    const f32x4 brc = *(const f32x4*)&b_ih[jc0]          + *(const f32x4*)&b_hh[jc0];
    const f32x4 bzc = *(const f32x4*)&b_ih[H_ + jc0]     + *(const f32x4*)&b_hh[H_ + jc0];
    const f32x4 bin = *(const f32x4*)&b_ih[2 * H_ + jc0];
    const f32x4 bhn = *(const f32x4*)&b_hh[2 * H_ + jc0];
    __syncthreads();

    const int swz = l15 << 4;
    auto arow = [&](int g, int kb) -> bf16x8 {
        return *(const bf16x8*)((const char*)Wlds + (g * 16 + l15) * 2560 + (kb ^ swz));
    };

    // wave0 x-projection (plain loads; compiler-managed waits), double-buffered
    f32x4 accXcur[3], accXnew[3];
    auto xgemm = [&](int t, f32x4* acc) {
        acc[0] = acc[1] = acc[2] = (f32x4){0.f, 0.f, 0.f, 0.f};
        const short* xp = xb + ((long)t * B_ + m0 + l15) * XD_ + lhi * 8;
        #pragma unroll
        for (int it = 0; it < 8; ++it) {
            bf16x8 bfrag = *(const bf16x8*)(xp + it * 32);
            const int kb = (it * 32 + lhi * 8) * 2;
            acc[0] = __builtin_amdgcn_mfma_f32_16x16x32_bf16(arow(0, kb), bfrag, acc[0], 0, 0, 0);
            acc[1] = __builtin_amdgcn_mfma_f32_16x16x32_bf16(arow(1, kb), bfrag, acc[1], 0, 0, 0);
            acc[2] = __builtin_amdgcn_mfma_f32_16x16x32_bf16(arow(2, kb), bfrag, acc[2], 0, 0, 0);
        }
    };
    if (w == 0) xgemm(0, accXcur);

    for (int t = 0; t < T_; ++t) {
        const int par = t & 1;

        // ---- wave1: 2-deep pipelined poll of domain's 64 flags (sc01) ----
        if (w == 1 && t > 0) {
            const int* fa = flags + dom * 64 + l15 * 4;
            i32x4 f0, f1;
            asm volatile("global_load_dwordx4 %0, %1, off sc0 sc1"
                         : "=&v"(f0) : "v"(fa) : "memory");
            __builtin_amdgcn_s_sleep(5);   // ~RT/2 stagger
            asm volatile("global_load_dwordx4 %0, %1, off sc0 sc1"
                         : "=&v"(f1) : "v"(fa) : "memory");
            while (true) {
                WAITV(1);   // f0 (oldest) retired
                int m01 = f0[0] < f0[1] ? f0[0] : f0[1];
                int m23 = f0[2] < f0[3] ? f0[2] : f0[3];
                int mn  = m01 < m23 ? m01 : m23;
                if (__all((l < 16) ? (mn >= t) : 1)) break;
                asm volatile("global_load_dwordx4 %0, %1, off sc0 sc1"
                             : "=&v"(f0) : "v"(fa) : "memory");
                WAITV(1);   // f1 (now oldest) retired
                m01 = f1[0] < f1[1] ? f1[0] : f1[1];
                m23 = f1[2] < f1[3] ? f1[2] : f1[3];
                mn  = m01 < m23 ? m01 : m23;
                if (__all((l < 16) ? (mn >= t) : 1)) break;
                asm volatile("global_load_dwordx4 %0, %1, off sc0 sc1"
                             : "=&v"(f1) : "v"(fa) : "memory");
            }
            asm volatile("s_waitcnt vmcnt(0)" ::: "memory");   // drain in-flight poll
        }
        __syncthreads();   // A: step-t h published (all 64 domain flags >= t)

        if (w == 0) {
            if (t + 1 < T_) xgemm(t + 1, accXnew);   // x(t+1) in the A->B window
        } else {
            f32x4 accH[3] = {{0.f,0.f,0.f,0.f},{0.f,0.f,0.f,0.f},{0.f,0.f,0.f,0.f}};
            if (t > 0) {
                auto hgemm = [&](auto ITC, int hk0) {
                    constexpr int IT = decltype(ITC)::value;
                    const short* hp = hbf16 + (long)par * (B_ * H_) + (m0 + l15) * H_ + hk0 + lhi * 8;
                    i32x4 hv[IT];
                    #pragma unroll
                    for (int it = 0; it < IT; ++it)
                        asm volatile("global_load_dwordx4 %0, %1, off sc0 sc1"
                                     : "=&v"(hv[it]) : "v"(hp + it * 32));
                    // pre-read all W fragments (LDS) while loads fly
                    bf16x8 wf[IT][3];
                    #pragma unroll
                    for (int it = 0; it < IT; ++it) {
                        const int kb = (256 + hk0 + it * 32 + lhi * 8) * 2;
                        wf[it][0] = arow(0, kb);
                        wf[it][1] = arow(1, kb);
                        wf[it][2] = arow(2, kb);
                    }
                    auto mf = [&](auto IC) {
                        constexpr int it = decltype(IC)::value;
                        union { i32x4 q; bf16x8 v; } uu; uu.q = hv[it];
                        accH[0] = __builtin_amdgcn_mfma_f32_16x16x32_bf16(wf[it][0], uu.v, accH[0], 0, 0, 0);
                        accH[1] = __builtin_amdgcn_mfma_f32_16x16x32_bf16(wf[it][1], uu.v, accH[1], 0, 0, 0);
                        accH[2] = __builtin_amdgcn_mfma_f32_16x16x32_bf16(wf[it][2], uu.v, accH[2], 0, 0, 0);
                    };
                    // counted vmcnt: start MFMA on chunk i as soon as its load lands
                    if constexpr (IT == 5) {
                        WAITV(4); mf(std::integral_constant<int,0>{});
                        WAITV(3); mf(std::integral_constant<int,1>{});
                        WAITV(2); mf(std::integral_constant<int,2>{});
                        WAITV(1); mf(std::integral_constant<int,3>{});
                        WAITV(0); mf(std::integral_constant<int,4>{});
                    } else {
                        WAITV(3); mf(std::integral_constant<int,0>{});
                        WAITV(2); mf(std::integral_constant<int,1>{});
                        WAITV(1); mf(std::integral_constant<int,2>{});
                        WAITV(0); mf(std::integral_constant<int,3>{});
                    }
                };
                // K=1024 over 7 waves; poller wave1 gets the smallest slice
                if      (w == 1) hgemm(std::integral_constant<int, 4>{}, 0);
                else if (w == 2) hgemm(std::integral_constant<int, 5>{}, 128);
                else if (w == 3) hgemm(std::integral_constant<int, 5>{}, 288);
                else if (w == 4) hgemm(std::integral_constant<int, 5>{}, 448);
                else if (w == 5) hgemm(std::integral_constant<int, 5>{}, 608);
                else if (w == 6) hgemm(std::integral_constant<int, 4>{}, 768);
                else             hgemm(std::integral_constant<int, 4>{}, 896);
            }
            #pragma unroll
            for (int g = 0; g < 3; ++g)
                *(f32x4*)&red[g][w - 1][l][0] = accH[g];
        }
        __syncthreads();   // B: partials of step t ready

        if (w == 0) {
            f32x4 Hr = {0.f,0.f,0.f,0.f}, Hz = {0.f,0.f,0.f,0.f}, Hn = {0.f,0.f,0.f,0.f};
            #pragma unroll
            for (int s = 0; s < 7; ++s) {
                Hr += *(const f32x4*)&red[0][s][l][0];
                Hz += *(const f32x4*)&red[1][s][l][0];
                Hn += *(const f32x4*)&red[2][s][l][0];
            }
            const int   p   = planl[t + 1];
            const float al  = (float)(p & 1);
            const float bet = (float)((p >> 1) & 1);
            const int   lg  = p >> 2;

            const f32x4 hb = *(const f32x4*)&hbls[par][l15][lhi * 4];
            f32x4 hn;
            #pragma unroll
            for (int r = 0; r < 4; ++r) {
                float rg = sigm_(accXcur[0][r] + Hr[r] + brc[r]);
                float zg = sigm_(accXcur[1][r] + Hz[r] + bzc[r]);
                float ng = tanh_(accXcur[2][r] + bin[r] + rg * (Hn[r] + bhn[r]));
                hn[r] = (1.f - zg) * ng + zg * hb[r];
            }
            // WG-local ring write (bf16), skip read, blend
            union { short s[4]; u64 q; } pk;
            #pragma unroll
            for (int r = 0; r < 4; ++r) pk.s[r] = bf16_of(hn[r]);
            *(bf16x4*)&ringl[t & 15][l15][lhi * 4] = *(bf16x4*)pk.s;
            const bf16x4 old4 = *(const bf16x4*)&ringl[(t + 1 - lg) & 15][l15][lhi * 4];
            f32x4 hbn;
            #pragma unroll
            for (int r = 0; r < 4; ++r)
                hbn[r] = al * hn[r] + bet * f_of_bf16(old4[r]);
            *(f32x4*)&hbls[par ^ 1][l15][lhi * 4] = hbn;

            if (t == T_ - 1) {
                f32x4 o;
                #pragma unroll
                for (int r = 0; r < 4; ++r) o[r] = 2.f * hn[r];
                float* op = out + (long)(m0 + l15) * H_ + jc0;
                asm volatile("global_store_dwordx4 %0, %1, off sc0 sc1"
                             :: "v"(op), "v"(o) : "memory");
            } else {
                // publish next-step h16 (sc01 -> MALL), ack, then flag store
                #pragma unroll
                for (int r = 0; r < 4; ++r) pk.s[r] = bf16_of(hbn[r]);
                short* pub = hbf16 + (long)(par ^ 1) * (B_ * H_) + (m0 + l15) * H_ + jc0;
                asm volatile("global_store_dwordx2 %0, %1, off sc0 sc1"
                             :: "v"(pub), "v"(pk.q) : "memory");
                asm volatile("s_waitcnt vmcnt(0)" ::: "memory");
                if (l == 0) {
                    int  fv = t + 1;
                    int* fp = flags + dom * 64 + cblk;
                    asm volatile("global_store_dword %0, %1, off sc0 sc1"
                                 :: "v"(fp), "v"(fv) : "memory");
                }
            }
            // rotate x pipeline (accXnew = x(t+1), computed in this step's window)
            accXcur[0] = accXnew[0]; accXcur[1] = accXnew[1]; accXcur[2] = accXnew[2];
        }
    }
}

extern "C" void kernel_launch(void* const* d_in, const int* in_sizes, int n_in,
                              void* d_out, int out_size, void* d_ws, size_t ws_size,
                              hipStream_t stream) {
    const float* x    = (const float*)d_in[0];
    const float* W_ih = (const float*)d_in[1];
    const float* W_hh = (const float*)d_in[2];
    const float* b_ih = (const float*)d_in[3];
    const float* b_hh = (const float*)d_in[4];
    const int*   w1   = (const int*)d_in[5];
    const int*   w2   = (const int*)d_in[6];
    const int*   ssp  = (const int*)d_in[7];
    float* out = (float*)d_out;

    char* ws = (char*)d_ws;
    short* Wcat  = (short*)(ws + OFF_WCAT);
    short* xbuf  = (short*)(ws + OFF_XB);
    short* hbf16 = (short*)(ws + OFF_HBF16);
    int*   plang = (int*)(ws + OFF_PLAN);
    int*   flags = (int*)(ws + OFF_FLAG);

    prep_wcat<<<3072, 256, 0, stream>>>(W_ih, W_hh, Wcat);
    prep_xb<<<8192, 256, 0, stream>>>(x, xbuf);
    prep_plan<<<1, 1024, 0, stream>>>(w1, w2, ssp, plang);
    prep_zero<<<256, 256, 0, stream>>>(hbf16, flags);

    persist_kernel<<<NWG, NTH, 0, stream>>>(Wcat, xbuf, b_ih, b_hh,
                                            hbf16, plang, flags, out);
}

// Round 16
// 2112.293 us; speedup vs baseline: 1.1168x; 1.1168x over previous
//
#include <hip/hip_runtime.h>
#include <hip/hip_bf16.h>
#include <type_traits>

typedef short bf16x8 __attribute__((ext_vector_type(8)));
typedef short bf16x4 __attribute__((ext_vector_type(4)));
typedef float f32x4  __attribute__((ext_vector_type(4)));
typedef int   i32x4  __attribute__((ext_vector_type(4)));
typedef unsigned long long u64;

#define B_   64
#define T_   512
#define XD_  256
#define H_   1024
#define NWG  256
#define NTH  512

// workspace layout (bytes)
#define OFF_WCAT  0UL
#define SZ_WCAT   (3072UL*1280*2)                 // 7,864,320
#define OFF_XB    (OFF_WCAT + SZ_WCAT)
#define SZ_XB     ((unsigned long)T_*B_*XD_*2)    // 16,777,216
#define OFF_HBF16 (OFF_XB + SZ_XB)
#define SZ_HBF16  (2UL*B_*H_*2)                   // 262,144
#define OFF_PLAN  (OFF_HBF16 + SZ_HBF16)
#define SZ_PLAN   (4096UL)
#define OFF_FLAG  (OFF_PLAN + SZ_PLAN)            // 4 domains x 64 ints (4 lines ea)
#define SZ_FLAG   (4096UL)

__device__ __forceinline__ float sigm_(float x) { return 1.f / (1.f + __expf(-x)); }
__device__ __forceinline__ float tanh_(float x) { return 1.f - 2.f / (__expf(2.f * x) + 1.f); }
__device__ __forceinline__ short bf16_of(float f) {
    __hip_bfloat16 h = __float2bfloat16(f);
    return *reinterpret_cast<short*>(&h);
}
__device__ __forceinline__ float f_of_bf16(short s) {
    union { unsigned u; float f; } c;
    c.u = ((unsigned)(unsigned short)s) << 16;
    return c.f;
}

// ---- prep: concat W_ih|W_hh into bf16 Wcat[3072][1280] ----
__global__ void prep_wcat(const float* __restrict__ W_ih, const float* __restrict__ W_hh,
                          short* __restrict__ Wcat) {
    const int j = blockIdx.x;
    for (int k = threadIdx.x; k < 1280; k += 256) {
        float v = (k < XD_) ? W_ih[j * XD_ + k] : W_hh[j * H_ + (k - XD_)];
        Wcat[(long)j * 1280 + k] = bf16_of(v);
    }
}

// ---- prep: transpose x [B][T][X] f32 -> xb [T][B][X] bf16 ----
__global__ void prep_xb(const float* __restrict__ x, short* __restrict__ xb) {
    const long total = (long)T_ * B_ * XD_;
    for (long i = (long)blockIdx.x * blockDim.x + threadIdx.x; i < total;
         i += (long)gridDim.x * blockDim.x) {
        int t   = (int)(i >> 14);
        int rem = (int)(i & 16383);
        int b   = rem >> 8;
        int k   = rem & 255;
        xb[i] = bf16_of(x[((long)(b * T_ + t)) * XD_ + k]);
    }
}

// ---- prep: packed per-step skip plan: bit0=alpha, bit1=beta, bits2+=lag ----
__global__ void prep_plan(const int* __restrict__ w1, const int* __restrict__ w2,
                          const int* __restrict__ ssp, int* __restrict__ plang) {
    int t = threadIdx.x;
    if (t > T_) return;
    if (t == T_) { plang[t] = (1 << 2); return; }
    int ss = ssp[0];
    int a = w1[t] & 1;
    int uz = 0, slot = 0;
    if (t < ss)            { if (2 * t < ss) uz = 1; else slot = ss - t - 1; }
    else if (t - ss < ss)  { uz = 1; }
    else                   { slot = 2 * ss - 1; }
    int bet = uz ? 0 : (w2[t] & 1);
    plang[t] = a | (bet << 1) | ((slot + 1) << 2);
}

// ---- prep: zero h16 slot0 + flags via sc01 (re-runs every graph replay) ----
__global__ void prep_zero(short* __restrict__ hbf16, int* __restrict__ flags) {
    int i = blockIdx.x * blockDim.x + threadIdx.x;
    if (i < B_ * H_) hbf16[i] = 0;
    if (i < 1024) {
        int* p = flags + i;
        int z = 0;
        asm volatile("global_store_dword %0, %1, off sc0 sc1" :: "v"(p), "v"(z) : "memory");
    }
}

// ---- persistent kernel: 256 WGs x 512 thr = 64 col-blocks x 4 batch-domains ----
// Final (R14): per-WG sc01 flag stores, wave1-only poll w/ backoff, sc01 MALL h
// exchange, wave0 x-GEMM of t+1 in the A->B window (double-buffered accs).
__global__ __launch_bounds__(NTH, 1) void persist_kernel(
    const short* __restrict__ Wcat, const short* __restrict__ xb,
    const float* __restrict__ b_ih, const float* __restrict__ b_hh,
    short* __restrict__ hbf16, const int* __restrict__ plang,
    int* __restrict__ flags, float* __restrict__ out) {

    __shared__ short Wlds[48 * 1280];        // 122,880 B (XOR-swizzled rows)
    __shared__ float red[3][7][64][4];       // 21,504 B  H partials (waves 1-7)
    __shared__ short ringl[16][16][20];      // 10,240 B  bf16 h history (skip path)
    __shared__ float hbls[2][16][20];        // 2,560 B   f32 blended-h (z path)
    __shared__ int   planl[T_ + 1];          // 2,052 B

    const int tid = threadIdx.x;
    const int w   = tid >> 6;           // wave 0..7
    const int l   = tid & 63;
    const int l15 = l & 15;
    const int lhi = l >> 4;
    const int wg  = blockIdx.x;
    const int c0  = (wg >> 2) << 4;     // 16 h-cols per WG
    const int m0  = (wg & 3) << 4;      // 16 batch rows per WG (sync domain)
    const int dom = wg & 3;
    const int cblk = wg >> 2;           // col-block 0..63
    const int jc0 = c0 + lhi * 4;

    // --- one-time: W slice -> LDS (swizzled: byte ^= (row&15)<<4), plan, zeros ---
    for (int j = tid; j < 48 * 160; j += NTH) {
        int r    = j / 160;
        int cbyt = (j - r * 160) * 16;
        int g    = r >> 4, i = r & 15;
        bf16x8 v = *(const bf16x8*)(Wcat + (long)(g * H_ + c0 + i) * 1280 + (cbyt >> 1));
        *(bf16x8*)((char*)Wlds + r * 2560 + (cbyt ^ (i << 4))) = v;
    }
    for (int j = tid; j <= T_; j += NTH) planl[j] = plang[j];
    for (int j = tid; j < 2 * 16 * 20; j += NTH) ((float*)hbls)[j] = 0.f;
    for (int j = tid; j < 16 * 16 * 20; j += NTH) ((short*)ringl)[j] = 0;

    const f32x4 brc = *(const f32x4*)&b_ih[jc0]          + *(const f32x4*)&b_hh[jc0];
    const f32x4 bzc = *(const f32x4*)&b_ih[H_ + jc0]     + *(const f32x4*)&b_hh[H_ + jc0];
    const f32x4 bin = *(const f32x4*)&b_ih[2 * H_ + jc0];
    const f32x4 bhn = *(const f32x4*)&b_hh[2 * H_ + jc0];
    __syncthreads();

    const int swz = l15 << 4;
    auto arow = [&](int g, int kb) -> bf16x8 {
        return *(const bf16x8*)((const char*)Wlds + (g * 16 + l15) * 2560 + (kb ^ swz));
    };

    // wave0 x-projection (plain loads; compiler-managed waits), double-buffered
    f32x4 accXcur[3], accXnew[3];
    auto xgemm = [&](int t, f32x4* acc) {
        acc[0] = acc[1] = acc[2] = (f32x4){0.f, 0.f, 0.f, 0.f};
        const short* xp = xb + ((long)t * B_ + m0 + l15) * XD_ + lhi * 8;
        #pragma unroll
        for (int it = 0; it < 8; ++it) {
            bf16x8 bfrag = *(const bf16x8*)(xp + it * 32);
            const int kb = (it * 32 + lhi * 8) * 2;
            acc[0] = __builtin_amdgcn_mfma_f32_16x16x32_bf16(arow(0, kb), bfrag, acc[0], 0, 0, 0);
            acc[1] = __builtin_amdgcn_mfma_f32_16x16x32_bf16(arow(1, kb), bfrag, acc[1], 0, 0, 0);
            acc[2] = __builtin_amdgcn_mfma_f32_16x16x32_bf16(arow(2, kb), bfrag, acc[2], 0, 0, 0);
        }
    };
    if (w == 0) xgemm(0, accXcur);

    for (int t = 0; t < T_; ++t) {
        const int par = t & 1;

        // ---- wave1 polls domain's 64 per-WG flags (sc01, backoff); others park at A ----
        if (w == 1 && t > 0) {
            const int* fa = flags + dom * 64 + l15 * 4;
            while (true) {
                i32x4 f;
                asm volatile("global_load_dwordx4 %0, %1, off sc0 sc1\n\t"
                             "s_waitcnt vmcnt(0)"
                             : "=&v"(f) : "v"(fa) : "memory");
                int m01 = f[0] < f[1] ? f[0] : f[1];
                int m23 = f[2] < f[3] ? f[2] : f[3];
                int mn  = m01 < m23 ? m01 : m23;
                if (__all((l < 16) ? (mn >= t) : 1)) break;
                __builtin_amdgcn_s_sleep(1);
            }
        }
        __syncthreads();   // A: step-t h published (all 64 domain flags >= t)

        if (w == 0) {
            if (t + 1 < T_) xgemm(t + 1, accXnew);   // x(t+1) in the A->B window
        } else {
            f32x4 accH[3] = {{0.f,0.f,0.f,0.f},{0.f,0.f,0.f,0.f},{0.f,0.f,0.f,0.f}};
            if (t > 0) {
                auto hgemm = [&](auto ITC, int hk0) {
                    constexpr int IT = decltype(ITC)::value;
                    const short* hp = hbf16 + (long)par * (B_ * H_) + (m0 + l15) * H_ + hk0 + lhi * 8;
                    i32x4 hv[IT];
                    #pragma unroll
                    for (int it = 0; it < IT; ++it)
                        asm volatile("global_load_dwordx4 %0, %1, off sc0 sc1"
                                     : "=&v"(hv[it]) : "v"(hp + it * 32));
                    asm volatile("s_waitcnt vmcnt(0)" ::: "memory");
                    __builtin_amdgcn_sched_barrier(0);
                    #pragma unroll
                    for (int it = 0; it < IT; ++it) {
                        union { i32x4 q; bf16x8 v; } uu; uu.q = hv[it];
                        const int kb = (256 + hk0 + it * 32 + lhi * 8) * 2;
                        accH[0] = __builtin_amdgcn_mfma_f32_16x16x32_bf16(arow(0, kb), uu.v, accH[0], 0, 0, 0);
                        accH[1] = __builtin_amdgcn_mfma_f32_16x16x32_bf16(arow(1, kb), uu.v, accH[1], 0, 0, 0);
                        accH[2] = __builtin_amdgcn_mfma_f32_16x16x32_bf16(arow(2, kb), uu.v, accH[2], 0, 0, 0);
                    }
                };
                // K=1024 over 7 waves: {160,160,160,160,128,128,128} cols
                if      (w == 1) hgemm(std::integral_constant<int, 5>{}, 0);
                else if (w == 2) hgemm(std::integral_constant<int, 5>{}, 160);
                else if (w == 3) hgemm(std::integral_constant<int, 5>{}, 320);
                else if (w == 4) hgemm(std::integral_constant<int, 5>{}, 480);
                else if (w == 5) hgemm(std::integral_constant<int, 4>{}, 640);
                else if (w == 6) hgemm(std::integral_constant<int, 4>{}, 768);
                else             hgemm(std::integral_constant<int, 4>{}, 896);
            }
            #pragma unroll
            for (int g = 0; g < 3; ++g)
                *(f32x4*)&red[g][w - 1][l][0] = accH[g];
        }
        __syncthreads();   // B: partials of step t ready

        if (w == 0) {
            f32x4 Hr = {0.f,0.f,0.f,0.f}, Hz = {0.f,0.f,0.f,0.f}, Hn = {0.f,0.f,0.f,0.f};
            #pragma unroll
            for (int s = 0; s < 7; ++s) {
                Hr += *(const f32x4*)&red[0][s][l][0];
                Hz += *(const f32x4*)&red[1][s][l][0];
                Hn += *(const f32x4*)&red[2][s][l][0];
            }
            const int   p   = planl[t + 1];
            const float al  = (float)(p & 1);
            const float bet = (float)((p >> 1) & 1);
            const int   lg  = p >> 2;

            const f32x4 hb = *(const f32x4*)&hbls[par][l15][lhi * 4];
            f32x4 hn;
            #pragma unroll
            for (int r = 0; r < 4; ++r) {
                float rg = sigm_(accXcur[0][r] + Hr[r] + brc[r]);
                float zg = sigm_(accXcur[1][r] + Hz[r] + bzc[r]);
                float ng = tanh_(accXcur[2][r] + bin[r] + rg * (Hn[r] + bhn[r]));
                hn[r] = (1.f - zg) * ng + zg * hb[r];
            }
            // WG-local ring write (bf16), skip read, blend
            union { short s[4]; u64 q; } pk;
            #pragma unroll
            for (int r = 0; r < 4; ++r) pk.s[r] = bf16_of(hn[r]);
            *(bf16x4*)&ringl[t & 15][l15][lhi * 4] = *(bf16x4*)pk.s;
            const bf16x4 old4 = *(const bf16x4*)&ringl[(t + 1 - lg) & 15][l15][lhi * 4];
            f32x4 hbn;
            #pragma unroll
            for (int r = 0; r < 4; ++r)
                hbn[r] = al * hn[r] + bet * f_of_bf16(old4[r]);
            *(f32x4*)&hbls[par ^ 1][l15][lhi * 4] = hbn;

            if (t == T_ - 1) {
                f32x4 o;
                #pragma unroll
                for (int r = 0; r < 4; ++r) o[r] = 2.f * hn[r];
                float* op = out + (long)(m0 + l15) * H_ + jc0;
                asm volatile("global_store_dwordx4 %0, %1, off sc0 sc1"
                             :: "v"(op), "v"(o) : "memory");
            } else {
                // publish next-step h16 (sc01 -> MALL), ack, then flag store
                #pragma unroll
                for (int r = 0; r < 4; ++r) pk.s[r] = bf16_of(hbn[r]);
                short* pub = hbf16 + (long)(par ^ 1) * (B_ * H_) + (m0 + l15) * H_ + jc0;
                asm volatile("global_store_dwordx2 %0, %1, off sc0 sc1"
                             :: "v"(pub), "v"(pk.q) : "memory");
                asm volatile("s_waitcnt vmcnt(0)" ::: "memory");
                if (l == 0) {
                    int  fv = t + 1;
                    int* fp = flags + dom * 64 + cblk;
                    asm volatile("global_store_dword %0, %1, off sc0 sc1"
                                 :: "v"(fp), "v"(fv) : "memory");
                }
            }
            // rotate x pipeline (accXnew = x(t+1), computed in this step's window)
            accXcur[0] = accXnew[0]; accXcur[1] = accXnew[1]; accXcur[2] = accXnew[2];
        }
    }
}

extern "C" void kernel_launch(void* const* d_in, const int* in_sizes, int n_in,
                              void* d_out, int out_size, void* d_ws, size_t ws_size,
                              hipStream_t stream) {
    const float* x    = (const float*)d_in[0];
    const float* W_ih = (const float*)d_in[1];
    const float* W_hh = (const float*)d_in[2];
    const float* b_ih = (const float*)d_in[3];
    const float* b_hh = (const float*)d_in[4];
    const int*   w1   = (const int*)d_in[5];
    const int*   w2   = (const int*)d_in[6];
    const int*   ssp  = (const int*)d_in[7];
    float* out = (float*)d_out;

    char* ws = (char*)d_ws;
    short* Wcat  = (short*)(ws + OFF_WCAT);
    short* xbuf  = (short*)(ws + OFF_XB);
    short* hbf16 = (short*)(ws + OFF_HBF16);
    int*   plang = (int*)(ws + OFF_PLAN);
    int*   flags = (int*)(ws + OFF_FLAG);

    prep_wcat<<<3072, 256, 0, stream>>>(W_ih, W_hh, Wcat);
    prep_xb<<<8192, 256, 0, stream>>>(x, xbuf);
    prep_plan<<<1, 1024, 0, stream>>>(w1, w2, ssp, plang);
    prep_zero<<<256, 256, 0, stream>>>(hbf16, flags);

    persist_kernel<<<NWG, NTH, 0, stream>>>(Wcat, xbuf, b_ih, b_hh,
                                            hbf16, plang, flags, out);
}